// Round 2
// baseline (196.864 us; speedup 1.0000x reference)
//
#include <hip/hip_runtime.h>

// Problem constants (from reference): N=32768, H=6, W=8, C=14
constexpr int   kN          = 32768;
constexpr int   kCells      = 32768 * 6 * 8;          // 1,572,864 cells
constexpr int   kC          = 14;
// 2 cells per thread: 28 floats = 7 float4 per tensor, contiguous & 16B-aligned.
constexpr int   kCellsThr   = 2;
constexpr int   kThreads    = kCells / kCellsThr;     // 786,432
constexpr int   kBlockSz    = 256;
constexpr int   kBlocks     = kThreads / kBlockSz;    // 3072 (exact)

constexpr float LAMBDA_COORD = 8.0f;
constexpr float LAMBDA_NOOBJ = 1.0f;
constexpr float LAMBDA_CLASS = 0.7f;
constexpr float EPS          = 1e-10f;

__device__ __forceinline__ float iou_box(float bx, float by, float bsw, float bsh,
                                         float gx, float gy, float gsw, float gsh) {
    float w1 = bsw * bsw, h1 = bsh * bsh;
    float w2 = gsw * gsw, h2 = gsh * gsh;
    float left  = fmaxf(bx - 0.5f * w1, gx - 0.5f * w2);
    float right = fminf(bx + 0.5f * w1, gx + 0.5f * w2);
    float top   = fmaxf(by - 0.5f * h1, gy - 0.5f * h2);
    float bot   = fminf(by + 0.5f * h1, gy + 0.5f * h2);
    float inter = fmaxf(right - left, 0.0f) * fmaxf(bot - top, 0.0f);
    float uni   = w1 * h1 + w2 * h2 - inter;
    return inter / (uni + EPS);
}

// Per-cell YOLO loss; o/g point into register arrays — with constant indices
// after full unroll this stays entirely in VGPRs.
__device__ __forceinline__ float cell_loss(const float* o, const float* g) {
    float obj   = (g[4] > 0.0f) ? 1.0f : 0.0f;
    float noobj = 1.0f - obj;

    float iou0 = iou_box(o[0], o[1], o[2], o[3], g[0], g[1], g[2], g[3]);
    float iou1 = iou_box(o[5], o[6], o[7], o[8], g[0], g[1], g[2], g[3]);
    bool  s1   = iou1 > iou0;              // argmax picks first on ties
    float max_iou = fmaxf(iou0, iou1);

    float pr0 = s1 ? o[5] : o[0];
    float pr1 = s1 ? o[6] : o[1];
    float pr2 = s1 ? o[7] : o[2];
    float pr3 = s1 ? o[8] : o[3];
    float pr4 = s1 ? o[9] : o[4];
    float po4 = s1 ? o[4] : o[9];

    float gr0 = s1 ? g[5] : g[0];
    float gr1 = s1 ? g[6] : g[1];
    float gr2 = s1 ? g[7] : g[2];
    float gr3 = s1 ? g[8] : g[3];
    float gn4 = s1 ? g[4] : g[9];

    float d4 = o[4] - g[4], d9 = o[9] - g[9];
    float no_loss = noobj * (d4 * d4 + d9 * d9);

    float dcf  = pr4 - max_iou;
    float conf = dcf * dcf;

    float l0 = pr0 - gr0, l1 = pr1 - gr1, l2 = pr2 - gr2, l3 = pr3 - gr3;
    float loc = l0 * l0 + l1 * l1 + l2 * l2 + l3 * l3;

    float dnb = po4 - gn4;
    float nbc = dnb * dnb;

    float cls = 0.0f;
#pragma unroll
    for (int c = 10; c < 14; ++c) { float d = o[c] - g[c]; cls += d * d; }

    return LAMBDA_NOOBJ * no_loss +
           obj * (conf + LAMBDA_COORD * loc + LAMBDA_NOOBJ * nbc + LAMBDA_CLASS * cls);
}

__global__ __launch_bounds__(kBlockSz) void yolo_partial(const float* __restrict__ outp,
                                                         const float* __restrict__ gtp,
                                                         float* __restrict__ partial) {
    __shared__ float red[4];

    const int    tid = threadIdx.x;
    const size_t t   = (size_t)blockIdx.x * kBlockSz + tid;

    // 14 independent dwordx4 loads straight into registers — no LDS, no barrier.
    const float4* go = reinterpret_cast<const float4*>(outp) + t * 7;
    const float4* gg = reinterpret_cast<const float4*>(gtp)  + t * 7;

    float4 ov[7], gv[7];
#pragma unroll
    for (int k = 0; k < 7; ++k) ov[k] = go[k];
#pragma unroll
    for (int k = 0; k < 7; ++k) gv[k] = gg[k];

    const float* of = reinterpret_cast<const float*>(ov);
    const float* gf = reinterpret_cast<const float*>(gv);

    float loss = 0.0f;
#pragma unroll
    for (int cell = 0; cell < kCellsThr; ++cell)
        loss += cell_loss(of + cell * kC, gf + cell * kC);

    // wave64 tree reduce -> block reduce
#pragma unroll
    for (int off = 32; off > 0; off >>= 1) loss += __shfl_down(loss, off, 64);
    if ((tid & 63) == 0) red[tid >> 6] = loss;
    __syncthreads();
    if (tid == 0) partial[blockIdx.x] = red[0] + red[1] + red[2] + red[3];
}

__global__ __launch_bounds__(256) void yolo_final(const float* __restrict__ partial,
                                                  float* __restrict__ out) {
    __shared__ double red[4];
    double acc = 0.0;
    for (int i = threadIdx.x; i < kBlocks; i += 256) acc += (double)partial[i];
#pragma unroll
    for (int off = 32; off > 0; off >>= 1) acc += __shfl_down(acc, off, 64);
    int tid = threadIdx.x;
    if ((tid & 63) == 0) red[tid >> 6] = acc;
    __syncthreads();
    if (tid == 0) out[0] = (float)((red[0] + red[1] + red[2] + red[3]) * (1.0 / (double)kN));
}

extern "C" void kernel_launch(void* const* d_in, const int* in_sizes, int n_in,
                              void* d_out, int out_size, void* d_ws, size_t ws_size,
                              hipStream_t stream) {
    const float* outp = (const float*)d_in[0];   // output: (N,H,W,C) fp32
    const float* gtp  = (const float*)d_in[1];   // ground_truth: (N,H,W,C) fp32
    float* partial    = (float*)d_ws;            // 3072 floats = 12 KB scratch
    float* out        = (float*)d_out;

    yolo_partial<<<kBlocks, kBlockSz, 0, stream>>>(outp, gtp, partial);
    yolo_final<<<1, 256, 0, stream>>>(partial, out);
}

// Round 3
// 196.752 us; speedup vs baseline: 1.0006x; 1.0006x over previous
//
#include <hip/hip_runtime.h>
#include <stdint.h>

// Problem constants (from reference): N=32768, H=6, W=8, C=14
constexpr int   kN          = 32768;
constexpr int   kCells      = 32768 * 6 * 8;      // 1,572,864 cells, 14 floats each
constexpr int   kC          = 14;

// Wave-private streaming design:
//   wave chunk = 128 cells = 1792 floats/tensor = 7168 B/tensor (7 x 1KB segments)
//   LDS per wave = 2 tensors * 7168 B = 14336 B; block = 4 waves -> 57344 B LDS
//   512 blocks = 2048 wave-slots; each slot streams 6 chunks = 768 cells
//   2048 * 768 = 1,572,864 = kCells (exact, no bounds checks)
constexpr int   kBlocks     = 512;
constexpr int   kWaveSlots  = kBlocks * 4;        // 2048
constexpr int   kChunks     = 6;                  // chunks per wave-slot
constexpr int   kChunkCells = 128;
constexpr int   kChunkFlts  = kChunkCells * kC;   // 1792 floats per tensor per chunk
constexpr int   kSlotFlts   = kChunks * kChunkFlts; // 10752 floats per tensor per slot

constexpr float LAMBDA_COORD = 8.0f;
constexpr float LAMBDA_NOOBJ = 1.0f;
constexpr float LAMBDA_CLASS = 0.7f;
constexpr float EPS          = 1e-10f;

// s_waitcnt immediates (gfx9/CDNA encoding: vm[3:0], exp[6:4], lgkm[11:8], vm[5:4]@[15:14])
#define WAITCNT_VM0    0x0f70   // vmcnt(0), lgkmcnt/expcnt = no-wait
#define WAITCNT_LGKM0  0xc07f   // lgkmcnt(0), vmcnt/expcnt = no-wait

__device__ __forceinline__ void load16_to_lds(const float* g, float* l) {
    // 16 B per lane, LDS dest = wave-uniform base + lane*16 (contiguous layout)
    __builtin_amdgcn_global_load_lds((void*)g, (void*)l, 16, 0, 0);
}

__device__ __forceinline__ float iou_box(float bx, float by, float bsw, float bsh,
                                         float gx, float gy, float gsw, float gsh) {
    float w1 = bsw * bsw, h1 = bsh * bsh;
    float w2 = gsw * gsw, h2 = gsh * gsh;
    float left  = fmaxf(bx - 0.5f * w1, gx - 0.5f * w2);
    float right = fminf(bx + 0.5f * w1, gx + 0.5f * w2);
    float top   = fmaxf(by - 0.5f * h1, gy - 0.5f * h2);
    float bot   = fminf(by + 0.5f * h1, gy + 0.5f * h2);
    float inter = fmaxf(right - left, 0.0f) * fmaxf(bot - top, 0.0f);
    float uni   = w1 * h1 + w2 * h2 - inter;
    return inter / (uni + EPS);
}

// Per-cell loss; o/g point into this wave's LDS region, constant offsets -> ds_read.
__device__ __forceinline__ float cell_loss(const float* __restrict__ o,
                                           const float* __restrict__ g) {
    float o0=o[0],o1=o[1],o2=o[2],o3=o[3],o4=o[4],o5=o[5],o6=o[6],o7=o[7],o8=o[8],o9=o[9];
    float g0=g[0],g1=g[1],g2=g[2],g3=g[3],g4=g[4],g5=g[5],g6=g[6],g7=g[7],g8=g[8],g9=g[9];

    float obj   = (g4 > 0.0f) ? 1.0f : 0.0f;
    float noobj = 1.0f - obj;

    float iou0 = iou_box(o0, o1, o2, o3, g0, g1, g2, g3);
    float iou1 = iou_box(o5, o6, o7, o8, g0, g1, g2, g3);
    bool  s1   = iou1 > iou0;                  // argmax picks first on ties
    float max_iou = fmaxf(iou0, iou1);

    float pr0 = s1 ? o5 : o0;
    float pr1 = s1 ? o6 : o1;
    float pr2 = s1 ? o7 : o2;
    float pr3 = s1 ? o8 : o3;
    float pr4 = s1 ? o9 : o4;
    float po4 = s1 ? o4 : o9;

    float gr0 = s1 ? g5 : g0;
    float gr1 = s1 ? g6 : g1;
    float gr2 = s1 ? g7 : g2;
    float gr3 = s1 ? g8 : g3;
    float gn4 = s1 ? g4 : g9;

    float d4 = o4 - g4, d9 = o9 - g9;
    float no_loss = noobj * (d4 * d4 + d9 * d9);

    float dcf  = pr4 - max_iou;
    float conf = dcf * dcf;

    float l0 = pr0 - gr0, l1 = pr1 - gr1, l2 = pr2 - gr2, l3 = pr3 - gr3;
    float loc = l0 * l0 + l1 * l1 + l2 * l2 + l3 * l3;

    float dnb = po4 - gn4;
    float nbc = dnb * dnb;

    float cls = 0.0f;
#pragma unroll
    for (int c = 10; c < 14; ++c) { float d = o[c] - g[c]; cls += d * d; }

    return LAMBDA_NOOBJ * no_loss +
           obj * (conf + LAMBDA_COORD * loc + LAMBDA_NOOBJ * nbc + LAMBDA_CLASS * cls);
}

__global__ __launch_bounds__(256) void yolo_partial(const float* __restrict__ outp,
                                                    const float* __restrict__ gtp,
                                                    float* __restrict__ partial) {
    // 4 wave-private regions: [O 1792 floats][G 1792 floats] each -> 57344 B
    __shared__ float s[4 * 2 * kChunkFlts];

    const int lane = threadIdx.x & 63;
    const int wave = threadIdx.x >> 6;

    float* sO = s + wave * (2 * kChunkFlts);
    float* sG = sO + kChunkFlts;

    const int    slot = blockIdx.x * 4 + wave;          // 0..2047
    const float* bO   = outp + (size_t)slot * kSlotFlts;
    const float* bG   = gtp  + (size_t)slot * kSlotFlts;

    float loss = 0.0f;

    for (int c = 0; c < kChunks; ++c) {
        if (c) __builtin_amdgcn_s_waitcnt(WAITCNT_LGKM0);   // prior chunk's ds_reads done
        const float* gO = bO + c * kChunkFlts;
        const float* gG = bG + c * kChunkFlts;
#pragma unroll
        for (int seg = 0; seg < 7; ++seg)
            load16_to_lds(gO + seg * 256 + lane * 4, sO + seg * 256);
#pragma unroll
        for (int seg = 0; seg < 7; ++seg)
            load16_to_lds(gG + seg * 256 + lane * 4, sG + seg * 256);

        __builtin_amdgcn_s_waitcnt(WAITCNT_VM0);            // this wave's loads landed

        // 2 cells per lane; wave-private region -> no barrier needed
        loss += cell_loss(sO + lane * kC,        sG + lane * kC);
        loss += cell_loss(sO + (lane + 64) * kC, sG + (lane + 64) * kC);
    }

    // wave64 tree reduce; one partial per wave-slot, no cross-wave traffic
#pragma unroll
    for (int off = 32; off > 0; off >>= 1) loss += __shfl_down(loss, off, 64);
    if (lane == 0) partial[slot] = loss;
}

__global__ __launch_bounds__(256) void yolo_final(const float* __restrict__ partial,
                                                  float* __restrict__ out) {
    __shared__ double red[4];
    double acc = 0.0;
    for (int i = threadIdx.x; i < kWaveSlots; i += 256) acc += (double)partial[i];
#pragma unroll
    for (int off = 32; off > 0; off >>= 1) acc += __shfl_down(acc, off, 64);
    int tid = threadIdx.x;
    if ((tid & 63) == 0) red[tid >> 6] = acc;
    __syncthreads();
    if (tid == 0) out[0] = (float)((red[0] + red[1] + red[2] + red[3]) * (1.0 / (double)kN));
}

extern "C" void kernel_launch(void* const* d_in, const int* in_sizes, int n_in,
                              void* d_out, int out_size, void* d_ws, size_t ws_size,
                              hipStream_t stream) {
    const float* outp = (const float*)d_in[0];   // output: (N,H,W,C) fp32
    const float* gtp  = (const float*)d_in[1];   // ground_truth: (N,H,W,C) fp32
    float* partial    = (float*)d_ws;            // 2048 floats = 8 KB scratch
    float* out        = (float*)d_out;

    yolo_partial<<<kBlocks, 256, 0, stream>>>(outp, gtp, partial);
    yolo_final<<<1, 256, 0, stream>>>(partial, out);
}

// Round 4
// 194.722 us; speedup vs baseline: 1.0110x; 1.0104x over previous
//
#include <hip/hip_runtime.h>
#include <stdint.h>

// Problem constants (from reference): N=32768, H=6, W=8, C=14
constexpr int   kN          = 32768;
constexpr int   kCells      = 32768 * 6 * 8;      // 1,572,864 cells, 14 floats each
constexpr int   kC          = 14;

// Wave-private DOUBLE-BUFFERED streaming:
//   chunk = 128 cells = 1792 floats/tensor = 7168 B/tensor (7 x 1KB segments)
//   wave LDS = 2 buffers x (O 7168 B + G 7168 B) = 28672 B
//   block = 1 wave (64 thr) -> 5 blocks/CU LDS cap; grid 1024 = 4/CU exact
//   each wave streams 12 chunks; 1024 * 12 * 128 = 1,572,864 = kCells (exact)
constexpr int   kSlots      = 1024;
constexpr int   kChunksSlot = 12;
constexpr int   kChunkCells = 128;
constexpr int   kChunkFlts  = kChunkCells * kC;        // 1792
constexpr int   kSlotFlts   = kChunksSlot * kChunkFlts; // 21504

constexpr float LAMBDA_COORD = 8.0f;
constexpr float LAMBDA_NOOBJ = 1.0f;
constexpr float LAMBDA_CLASS = 0.7f;
constexpr float EPS          = 1e-10f;

// s_waitcnt immediates (gfx9/CDNA: vm[3:0]@[3:0], exp@[6:4], lgkm@[11:8], vm[5:4]@[15:14])
#define WAITCNT_VM0    0x0f70   // vmcnt(0), others no-wait   (verified working R3)
#define WAITCNT_VM14   0x0f7e   // vmcnt(14): oldest chunk landed, newest 14 may fly
#define WAITCNT_LGKM0  0xc07f   // lgkmcnt(0), others no-wait

__device__ __forceinline__ void load16_to_lds(const float* g, float* l) {
    // 16 B/lane, LDS dest = wave-uniform base + lane*16 (contiguous layout)
    __builtin_amdgcn_global_load_lds((void*)g, (void*)l, 16, 0, 0);
}

// Issue one chunk (14 x global_load_lds_dwordx4 = 14336 B) into [dstO | dstG]
__device__ __forceinline__ void issue_chunk(const float* bO, const float* bG, int c,
                                            float* dstO, int lane) {
    const float* gO = bO + c * kChunkFlts;
    const float* gG = bG + c * kChunkFlts;
    float* dstG = dstO + kChunkFlts;
#pragma unroll
    for (int seg = 0; seg < 7; ++seg)
        load16_to_lds(gO + seg * 256 + lane * 4, dstO + seg * 256);
#pragma unroll
    for (int seg = 0; seg < 7; ++seg)
        load16_to_lds(gG + seg * 256 + lane * 4, dstG + seg * 256);
}

__device__ __forceinline__ float iou_box(float bx, float by, float bsw, float bsh,
                                         float gx, float gy, float gsw, float gsh) {
    float w1 = bsw * bsw, h1 = bsh * bsh;
    float w2 = gsw * gsw, h2 = gsh * gsh;
    float left  = fmaxf(bx - 0.5f * w1, gx - 0.5f * w2);
    float right = fminf(bx + 0.5f * w1, gx + 0.5f * w2);
    float top   = fmaxf(by - 0.5f * h1, gy - 0.5f * h2);
    float bot   = fminf(by + 0.5f * h1, gy + 0.5f * h2);
    float inter = fmaxf(right - left, 0.0f) * fmaxf(bot - top, 0.0f);
    float uni   = w1 * h1 + w2 * h2 - inter;
    return inter / (uni + EPS);
}

__device__ __forceinline__ float cell_loss(const float* __restrict__ o,
                                           const float* __restrict__ g) {
    float o0=o[0],o1=o[1],o2=o[2],o3=o[3],o4=o[4],o5=o[5],o6=o[6],o7=o[7],o8=o[8],o9=o[9];
    float g0=g[0],g1=g[1],g2=g[2],g3=g[3],g4=g[4],g5=g[5],g6=g[6],g7=g[7],g8=g[8],g9=g[9];

    float obj   = (g4 > 0.0f) ? 1.0f : 0.0f;
    float noobj = 1.0f - obj;

    float iou0 = iou_box(o0, o1, o2, o3, g0, g1, g2, g3);
    float iou1 = iou_box(o5, o6, o7, o8, g0, g1, g2, g3);
    bool  s1   = iou1 > iou0;                  // argmax picks first on ties
    float max_iou = fmaxf(iou0, iou1);

    float pr0 = s1 ? o5 : o0;
    float pr1 = s1 ? o6 : o1;
    float pr2 = s1 ? o7 : o2;
    float pr3 = s1 ? o8 : o3;
    float pr4 = s1 ? o9 : o4;
    float po4 = s1 ? o4 : o9;

    float gr0 = s1 ? g5 : g0;
    float gr1 = s1 ? g6 : g1;
    float gr2 = s1 ? g7 : g2;
    float gr3 = s1 ? g8 : g3;
    float gn4 = s1 ? g4 : g9;

    float d4 = o4 - g4, d9 = o9 - g9;
    float no_loss = noobj * (d4 * d4 + d9 * d9);

    float dcf  = pr4 - max_iou;
    float conf = dcf * dcf;

    float l0 = pr0 - gr0, l1 = pr1 - gr1, l2 = pr2 - gr2, l3 = pr3 - gr3;
    float loc = l0 * l0 + l1 * l1 + l2 * l2 + l3 * l3;

    float dnb = po4 - gn4;
    float nbc = dnb * dnb;

    float cls = 0.0f;
#pragma unroll
    for (int c = 10; c < 14; ++c) { float d = o[c] - g[c]; cls += d * d; }

    return LAMBDA_NOOBJ * no_loss +
           obj * (conf + LAMBDA_COORD * loc + LAMBDA_NOOBJ * nbc + LAMBDA_CLASS * cls);
}

__global__ __launch_bounds__(64) void yolo_partial(const float* __restrict__ outp,
                                                   const float* __restrict__ gtp,
                                                   float* __restrict__ partial) {
    // double buffer: [buf0: O|G][buf1: O|G] = 4 * 1792 floats = 28672 B
    __shared__ float s[4 * kChunkFlts];

    const int lane = threadIdx.x;                 // block = exactly 1 wave
    const int slot = blockIdx.x;

    const float* bO = outp + (size_t)slot * kSlotFlts;
    const float* bG = gtp  + (size_t)slot * kSlotFlts;

    float* buf0 = s;
    float* buf1 = s + 2 * kChunkFlts;

    // Prime the pipeline: chunks 0 and 1 in flight (28 loads, 28.7 KB)
    issue_chunk(bO, bG, 0, buf0, lane);
    issue_chunk(bO, bG, 1, buf1, lane);

    float loss = 0.0f;

    for (int c = 0; c < kChunksSlot; ++c) {
        // Wait only for the OLDEST chunk; the newest 14 loads keep streaming.
        if (c == kChunksSlot - 1) __builtin_amdgcn_s_waitcnt(WAITCNT_VM0);
        else                      __builtin_amdgcn_s_waitcnt(WAITCNT_VM14);

        float* buf = (c & 1) ? buf1 : buf0;
        loss += cell_loss(buf + lane * kC,        buf + kChunkFlts + lane * kC);
        loss += cell_loss(buf + (lane + 64) * kC, buf + kChunkFlts + (lane + 64) * kC);

        if (c + 2 < kChunksSlot) {
            // LDS reads of this buffer must land before overwrite (wave-local)
            __builtin_amdgcn_s_waitcnt(WAITCNT_LGKM0);
            issue_chunk(bO, bG, c + 2, buf, lane);
        }
    }

    // wave64 tree reduce; one partial per wave-slot
#pragma unroll
    for (int off = 32; off > 0; off >>= 1) loss += __shfl_down(loss, off, 64);
    if (lane == 0) partial[slot] = loss;
}

__global__ __launch_bounds__(256) void yolo_final(const float* __restrict__ partial,
                                                  float* __restrict__ out) {
    __shared__ double red[4];
    double acc = 0.0;
    for (int i = threadIdx.x; i < kSlots; i += 256) acc += (double)partial[i];
#pragma unroll
    for (int off = 32; off > 0; off >>= 1) acc += __shfl_down(acc, off, 64);
    int tid = threadIdx.x;
    if ((tid & 63) == 0) red[tid >> 6] = acc;
    __syncthreads();
    if (tid == 0) out[0] = (float)((red[0] + red[1] + red[2] + red[3]) * (1.0 / (double)kN));
}

extern "C" void kernel_launch(void* const* d_in, const int* in_sizes, int n_in,
                              void* d_out, int out_size, void* d_ws, size_t ws_size,
                              hipStream_t stream) {
    const float* outp = (const float*)d_in[0];   // output: (N,H,W,C) fp32
    const float* gtp  = (const float*)d_in[1];   // ground_truth: (N,H,W,C) fp32
    float* partial    = (float*)d_ws;            // 1024 floats = 4 KB scratch
    float* out        = (float*)d_out;

    yolo_partial<<<kSlots, 64, 0, stream>>>(outp, gtp, partial);
    yolo_final<<<1, 256, 0, stream>>>(partial, out);
}